// Round 1
// baseline (1217.083 us; speedup 1.0000x reference)
//
#include <hip/hip_runtime.h>
#include <math.h>

#define IN_F 64
#define HID 128
#define NCLS 10

// ---------------- degree ----------------
__global__ void k_init_deg(float* __restrict__ deg, int n) {
    int i = blockIdx.x * blockDim.x + threadIdx.x;
    if (i < n) deg[i] = 1.0f;  // self-loop contributes 1
}

__global__ void k_count_deg(const int* __restrict__ col, float* __restrict__ deg, int E) {
    int i = blockIdx.x * blockDim.x + threadIdx.x;
    if (i < E) atomicAdd(&deg[col[i]], 1.0f);
}

__global__ void k_rsqrt(float* __restrict__ deg, int n) {
    int i = blockIdx.x * blockDim.x + threadIdx.x;
    if (i < n) deg[i] = rsqrtf(deg[i]);  // deg >= 1 always
}

// ---------------- GEMM1: h[N,128] = x[N,64] @ W1[64,128] ----------------
// one thread per (node, 4 output cols)
__global__ void k_gemm1(const float* __restrict__ x, const float* __restrict__ W1,
                        float* __restrict__ h, int n) {
    int idx = blockIdx.x * blockDim.x + threadIdx.x;
    int node = idx >> 5;          // 32 groups of 4 cols per node
    int j4 = (idx & 31) << 2;
    if (node >= n) return;
    const float* xr = x + (size_t)node * IN_F;
    float a0 = 0.f, a1 = 0.f, a2 = 0.f, a3 = 0.f;
#pragma unroll
    for (int k = 0; k < IN_F; ++k) {
        float xv = xr[k];
        float4 w = *(const float4*)(W1 + (size_t)k * HID + j4);
        a0 = fmaf(xv, w.x, a0);
        a1 = fmaf(xv, w.y, a1);
        a2 = fmaf(xv, w.z, a2);
        a3 = fmaf(xv, w.w, a3);
    }
    float4 r = make_float4(a0, a1, a2, a3);
    *(float4*)(h + (size_t)node * HID + j4) = r;
}

// ---------------- agg1 init: b1 + self-loop ----------------
__global__ void k_self1(const float* __restrict__ h, const float* __restrict__ dis,
                        const float* __restrict__ b1, float* __restrict__ agg, int n) {
    int idx = blockIdx.x * blockDim.x + threadIdx.x;
    int node = idx >> 7;
    int j = idx & (HID - 1);
    if (node >= n) return;
    float d = dis[node];
    agg[idx] = b1[j] + h[idx] * d * d;
}

// ---------------- edge scatter layer 1 (128 feats) ----------------
__global__ void k_scatter1(const int* __restrict__ row, const int* __restrict__ col,
                           const float* __restrict__ dis, const float* __restrict__ h,
                           float* __restrict__ agg, int E) {
    long long t = (long long)blockIdx.x * blockDim.x + threadIdx.x;
    int e = (int)(t >> 7);
    int j = (int)(t & (HID - 1));
    if (e >= E) return;
    int r = row[e];
    int c = col[e];
    float norm = dis[r] * dis[c];
    atomicAdd(&agg[(size_t)c * HID + j], h[(size_t)r * HID + j] * norm);
}

// ---------------- GEMM2: h2[N,10] = relu(agg1) @ W2[128,10] ----------------
__global__ void k_gemm2(const float* __restrict__ a, const float* __restrict__ W2,
                        float* __restrict__ h2, int n) {
    int idx = blockIdx.x * blockDim.x + threadIdx.x;
    if (idx >= n * NCLS) return;
    int node = idx / NCLS;
    int c = idx - node * NCLS;
    const float* ar = a + (size_t)node * HID;
    float acc = 0.f;
#pragma unroll
    for (int k = 0; k < HID; ++k) {
        acc = fmaf(fmaxf(ar[k], 0.f), W2[k * NCLS + c], acc);
    }
    h2[idx] = acc;
}

// ---------------- agg2 init: b2 + self-loop ----------------
__global__ void k_self2(const float* __restrict__ h2, const float* __restrict__ dis,
                        const float* __restrict__ b2, float* __restrict__ agg2, int n) {
    int idx = blockIdx.x * blockDim.x + threadIdx.x;
    if (idx >= n * NCLS) return;
    int node = idx / NCLS;
    int c = idx - node * NCLS;
    float d = dis[node];
    agg2[idx] = b2[c] + h2[idx] * d * d;
}

// ---------------- edge scatter layer 2 (10 feats) ----------------
__global__ void k_scatter2(const int* __restrict__ row, const int* __restrict__ col,
                           const float* __restrict__ dis, const float* __restrict__ h2,
                           float* __restrict__ agg2, int E) {
    long long t = (long long)blockIdx.x * blockDim.x + threadIdx.x;
    int e = (int)(t / NCLS);
    int c = (int)(t - (long long)e * NCLS);
    if (e >= E) return;
    int r = row[e];
    int cl = col[e];
    float norm = dis[r] * dis[cl];
    atomicAdd(&agg2[(size_t)cl * NCLS + c], h2[(size_t)r * NCLS + c] * norm);
}

// ---------------- output zero ----------------
__global__ void k_zero_out(float* __restrict__ out) {
    if (threadIdx.x < NCLS) out[threadIdx.x] = 0.f;
}

// ---------------- log-softmax + mean reduce ----------------
__global__ void k_lsm(const float* __restrict__ agg2, float* __restrict__ out,
                      int n, float inv_n) {
    __shared__ float s[NCLS];
    if (threadIdx.x < NCLS) s[threadIdx.x] = 0.f;
    __syncthreads();
    float loc[NCLS];
#pragma unroll
    for (int c = 0; c < NCLS; ++c) loc[c] = 0.f;
    for (int i = blockIdx.x * blockDim.x + threadIdx.x; i < n;
         i += gridDim.x * blockDim.x) {
        const float* v = agg2 + (size_t)i * NCLS;
        float vv[NCLS];
        float m = v[0];
#pragma unroll
        for (int c = 1; c < NCLS; ++c) m = fmaxf(m, v[c]);
        float se = 0.f;
#pragma unroll
        for (int c = 0; c < NCLS; ++c) {
            vv[c] = v[c] - m;
            se += __expf(vv[c]);
        }
        float lse = __logf(se);
#pragma unroll
        for (int c = 0; c < NCLS; ++c) loc[c] += vv[c] - lse;
    }
#pragma unroll
    for (int c = 0; c < NCLS; ++c) atomicAdd(&s[c], loc[c]);
    __syncthreads();
    if (threadIdx.x < NCLS) atomicAdd(&out[threadIdx.x], s[threadIdx.x] * inv_n);
}

extern "C" void kernel_launch(void* const* d_in, const int* in_sizes, int n_in,
                              void* d_out, int out_size, void* d_ws, size_t ws_size,
                              hipStream_t stream) {
    const float* x = (const float*)d_in[0];
    const int* eidx = (const int*)d_in[1];
    const float* W1 = (const float*)d_in[2];
    const float* b1 = (const float*)d_in[3];
    const float* W2 = (const float*)d_in[4];
    const float* b2 = (const float*)d_in[5];
    float* out = (float*)d_out;

    const int N = in_sizes[0] / IN_F;       // 100000
    const int E = in_sizes[1] / 2;          // 1600000
    const int* row = eidx;                  // edge_index[0] = sources
    const int* col = eidx + E;              // edge_index[1] = targets

    // workspace layout (floats)
    float* ws = (float*)d_ws;
    size_t OFF_DIS = 0;
    size_t OFF_H = 100096;                          // N rounded up, aligned
    size_t OFF_AGG1 = OFF_H + (size_t)N * HID;      // h dead after scatter1 ...
    size_t OFF_H2 = OFF_H;                          // ... so h2 reuses h region
    size_t OFF_AGG2 = OFF_AGG1 + (size_t)N * HID;
    float* dis = ws + OFF_DIS;
    float* h = ws + OFF_H;
    float* agg1 = ws + OFF_AGG1;
    float* h2 = ws + OFF_H2;
    float* agg2 = ws + OFF_AGG2;

    const int B = 256;

    // degrees
    k_init_deg<<<(N + B - 1) / B, B, 0, stream>>>(dis, N);
    k_count_deg<<<(E + B - 1) / B, B, 0, stream>>>(col, dis, E);
    k_rsqrt<<<(N + B - 1) / B, B, 0, stream>>>(dis, N);

    // layer 1
    {
        long long threads = (long long)N * 32;
        k_gemm1<<<(unsigned)((threads + B - 1) / B), B, 0, stream>>>(x, W1, h, N);
    }
    {
        long long threads = (long long)N * HID;
        k_self1<<<(unsigned)((threads + B - 1) / B), B, 0, stream>>>(h, dis, b1, agg1, N);
    }
    {
        long long threads = (long long)E * HID;
        k_scatter1<<<(unsigned)((threads + B - 1) / B), B, 0, stream>>>(row, col, dis, h,
                                                                        agg1, E);
    }

    // layer 2 (h2 overwrites h region — h no longer needed)
    {
        long long threads = (long long)N * NCLS;
        k_gemm2<<<(unsigned)((threads + B - 1) / B), B, 0, stream>>>(agg1, W2, h2, N);
        k_self2<<<(unsigned)((threads + B - 1) / B), B, 0, stream>>>(h2, dis, b2, agg2, N);
    }
    {
        long long threads = (long long)E * NCLS;
        k_scatter2<<<(unsigned)((threads + B - 1) / B), B, 0, stream>>>(row, col, dis, h2,
                                                                        agg2, E);
    }

    // output
    k_zero_out<<<1, 64, 0, stream>>>(out);
    k_lsm<<<1024, B, 0, stream>>>(agg2, out, N, 1.0f / (float)N);
}

// Round 2
// 590.998 us; speedup vs baseline: 2.0594x; 2.0594x over previous
//
#include <hip/hip_runtime.h>
#include <math.h>

#define IN_F 64
#define HID 128
#define NCLS 10

// ---------- utility ----------
__global__ void k_zero_int(int* __restrict__ p, int n) {
    int i = blockIdx.x * blockDim.x + threadIdx.x;
    if (i < n) p[i] = 0;
}

__global__ void k_zero_out(float* __restrict__ out) {
    if (threadIdx.x < NCLS) out[threadIdx.x] = 0.f;
}

// ---------- degree histogram over targets ----------
__global__ void k_hist(const int* __restrict__ col, int* __restrict__ cnt, int E) {
    int i = blockIdx.x * blockDim.x + threadIdx.x;
    if (i < E) atomicAdd(&cnt[col[i]], 1);
}

__global__ void k_dis(const int* __restrict__ cnt, float* __restrict__ dis, int n) {
    int i = blockIdx.x * blockDim.x + threadIdx.x;
    if (i < n) dis[i] = rsqrtf(1.0f + (float)cnt[i]);  // +1 self-loop
}

// ---------- 3-kernel exclusive scan (cnt -> rowptr) ----------
__global__ void k_blocksum(const int* __restrict__ cnt, int* __restrict__ bsum, int n) {
    __shared__ int s[256];
    int i = blockIdx.x * 256 + threadIdx.x;
    s[threadIdx.x] = (i < n) ? cnt[i] : 0;
    __syncthreads();
    for (int off = 128; off > 0; off >>= 1) {
        if (threadIdx.x < off) s[threadIdx.x] += s[threadIdx.x + off];
        __syncthreads();
    }
    if (threadIdx.x == 0) bsum[blockIdx.x] = s[0];
}

__global__ void k_scan_bsum(const int* __restrict__ bsum, int* __restrict__ boff, int nb,
                            int* __restrict__ rowptr, int n, int E) {
    __shared__ int s[512];
    int t = threadIdx.x;
    int v = (t < nb) ? bsum[t] : 0;
    s[t] = v;
    __syncthreads();
    for (int off = 1; off < 512; off <<= 1) {
        int tmp = (t >= off) ? s[t - off] : 0;
        __syncthreads();
        s[t] += tmp;
        __syncthreads();
    }
    if (t < nb) boff[t] = s[t] - v;  // exclusive
    if (t == 0) rowptr[n] = E;
}

__global__ void k_scan_final(const int* __restrict__ cnt, const int* __restrict__ boff,
                             int* __restrict__ rowptr, int n) {
    __shared__ int s[256];
    int i = blockIdx.x * 256 + threadIdx.x;
    int v = (i < n) ? cnt[i] : 0;
    s[threadIdx.x] = v;
    __syncthreads();
    for (int off = 1; off < 256; off <<= 1) {
        int tmp = (threadIdx.x >= off) ? s[threadIdx.x - off] : 0;
        __syncthreads();
        s[threadIdx.x] += tmp;
        __syncthreads();
    }
    if (i < n) rowptr[i] = boff[blockIdx.x] + s[threadIdx.x] - v;  // exclusive
}

// ---------- CSR fill: src list sorted by target ----------
__global__ void k_fill(const int* __restrict__ row, const int* __restrict__ col,
                       const int* __restrict__ rowptr, int* __restrict__ pos,
                       int* __restrict__ src, int E) {
    int e = blockIdx.x * blockDim.x + threadIdx.x;
    if (e >= E) return;
    int c = col[e];
    int p = rowptr[c] + atomicAdd(&pos[c], 1);
    src[p] = row[e];
}

// ---------- xs = x * dis[node] ----------
__global__ void k_xs(const float* __restrict__ x, const float* __restrict__ dis,
                     float* __restrict__ xs, int n16) {
    int i = blockIdx.x * blockDim.x + threadIdx.x;
    if (i >= n16) return;
    float d = dis[i >> 4];  // 16 float4s per node (64 feats)
    float4 v = ((const float4*)x)[i];
    v.x *= d; v.y *= d; v.z *= d; v.w *= d;
    ((float4*)xs)[i] = v;
}

// ---------- fused gather1 + GEMM1 + bias + relu ----------
// one wave per node; lane = input feature; LDS hands the aggregated row to GEMM
__global__ __launch_bounds__(256) void k_l1(const float* __restrict__ xs,
                                            const int* __restrict__ src,
                                            const int* __restrict__ rowptr,
                                            const float* __restrict__ dis,
                                            const float* __restrict__ W1,
                                            const float* __restrict__ b1,
                                            float* __restrict__ h, int n) {
    __shared__ float hacc[4][64];
    int w = threadIdx.x >> 6, lane = threadIdx.x & 63;
    int i = blockIdx.x * 4 + w;
    float acc = 0.f, d = 0.f;
    if (i < n) {
        acc = xs[(size_t)i * IN_F + lane];  // self-loop term
        d = dis[i];
        int beg = rowptr[i], end = rowptr[i + 1];
        for (int e = beg; e < end; ++e) {
            int s = src[e];
            acc += xs[(size_t)s * IN_F + lane];
        }
    }
    hacc[w][lane] = acc * d;  // post-scale by dis[target]
    __syncthreads();
    if (i < n) {
        float h0 = b1[lane], h1 = b1[lane + 64];
#pragma unroll
        for (int k = 0; k < IN_F; ++k) {
            float a = hacc[w][k];  // LDS broadcast
            h0 = fmaf(a, W1[k * HID + lane], h0);
            h1 = fmaf(a, W1[k * HID + lane + 64], h1);
        }
        h[(size_t)i * HID + lane] = fmaxf(h0, 0.f);
        h[(size_t)i * HID + lane + 64] = fmaxf(h1, 0.f);
    }
}

// ---------- h2s[i,c] = dis[i] * sum_k h[i,k] W2[k,c] ----------
__global__ void k_h2s(const float* __restrict__ h, const float* __restrict__ W2,
                      const float* __restrict__ dis, float* __restrict__ h2s, int n) {
    int idx = blockIdx.x * blockDim.x + threadIdx.x;
    if (idx >= n * NCLS) return;
    int node = idx / NCLS;
    int c = idx - node * NCLS;
    const float* hr = h + (size_t)node * HID;
    float acc = 0.f;
#pragma unroll
    for (int k = 0; k < HID; k += 4) {
        float4 hv = *(const float4*)(hr + k);
        acc = fmaf(hv.x, W2[(k + 0) * NCLS + c], acc);
        acc = fmaf(hv.y, W2[(k + 1) * NCLS + c], acc);
        acc = fmaf(hv.z, W2[(k + 2) * NCLS + c], acc);
        acc = fmaf(hv.w, W2[(k + 3) * NCLS + c], acc);
    }
    h2s[idx] = acc * dis[node];
}

// ---------- fused gather2 + b2 + log-softmax + mean-reduce ----------
__global__ void k_lsm2(const float* __restrict__ h2s, const int* __restrict__ src,
                       const int* __restrict__ rowptr, const float* __restrict__ dis,
                       const float* __restrict__ b2, float* __restrict__ out, int n,
                       float inv_n) {
    __shared__ float sred[NCLS];
    if (threadIdx.x < NCLS) sred[threadIdx.x] = 0.f;
    __syncthreads();
    int i = blockIdx.x * blockDim.x + threadIdx.x;
    float loc[NCLS];
#pragma unroll
    for (int c = 0; c < NCLS; ++c) loc[c] = 0.f;
    if (i < n) {
        float a[NCLS];
        const float* self = h2s + (size_t)i * NCLS;
#pragma unroll
        for (int c = 0; c < NCLS; c += 2) {
            float2 v = *(const float2*)(self + c);
            a[c] = v.x;
            a[c + 1] = v.y;
        }
        int beg = rowptr[i], end = rowptr[i + 1];
        for (int e = beg; e < end; ++e) {
            const float* p = h2s + (size_t)src[e] * NCLS;
#pragma unroll
            for (int c = 0; c < NCLS; c += 2) {
                float2 v = *(const float2*)(p + c);
                a[c] += v.x;
                a[c + 1] += v.y;
            }
        }
        float d = dis[i];
        float vv[NCLS];
        float m = -1e30f;
#pragma unroll
        for (int c = 0; c < NCLS; ++c) {
            vv[c] = b2[c] + d * a[c];
            m = fmaxf(m, vv[c]);
        }
        float se = 0.f;
#pragma unroll
        for (int c = 0; c < NCLS; ++c) se += __expf(vv[c] - m);
        float lse = m + __logf(se);
#pragma unroll
        for (int c = 0; c < NCLS; ++c) loc[c] = vv[c] - lse;
    }
#pragma unroll
    for (int c = 0; c < NCLS; ++c) atomicAdd(&sred[c], loc[c]);
    __syncthreads();
    if (threadIdx.x < NCLS) atomicAdd(&out[threadIdx.x], sred[threadIdx.x] * inv_n);
}

extern "C" void kernel_launch(void* const* d_in, const int* in_sizes, int n_in,
                              void* d_out, int out_size, void* d_ws, size_t ws_size,
                              hipStream_t stream) {
    const float* x = (const float*)d_in[0];
    const int* eidx = (const int*)d_in[1];
    const float* W1 = (const float*)d_in[2];
    const float* b1 = (const float*)d_in[3];
    const float* W2 = (const float*)d_in[4];
    const float* b2 = (const float*)d_in[5];
    float* out = (float*)d_out;

    const int N = in_sizes[0] / IN_F;  // 100000
    const int E = in_sizes[1] / 2;     // 1600000
    const int* row = eidx;             // sources
    const int* col = eidx + E;         // targets

    const int NB = (N + 255) / 256;  // scan blocks (391 <= 512)

    // workspace layout (4-byte words, 1024-word aligned)
    size_t o = 0;
    auto alloc = [&](size_t words) {
        size_t r = o;
        o += (words + 1023) & ~(size_t)1023;
        return r;
    };
    float* ws = (float*)d_ws;
    float* dis = ws + alloc(N);
    float* xs = ws + alloc((size_t)N * IN_F);
    float* h = ws + alloc((size_t)N * HID);
    float* h2s = ws + alloc((size_t)N * NCLS);
    int* src = (int*)(ws + alloc(E));
    int* rowptr = (int*)(ws + alloc(N + 1));
    int* cnt = (int*)(ws + alloc(N));
    int* pos = (int*)(ws + alloc(N));
    int* bsum = (int*)(ws + alloc(1024));
    int* boff = (int*)(ws + alloc(1024));

    const int B = 256;

    // ---- CSR build + degrees ----
    k_zero_int<<<(2 * N + B - 1) / B, B, 0, stream>>>(cnt, 2 * N);  // cnt & pos adjacent? no
    k_zero_int<<<(N + B - 1) / B, B, 0, stream>>>(pos, N);
    k_hist<<<(E + B - 1) / B, B, 0, stream>>>(col, cnt, E);
    k_dis<<<(N + B - 1) / B, B, 0, stream>>>(cnt, dis, N);
    k_blocksum<<<NB, 256, 0, stream>>>(cnt, bsum, N);
    k_scan_bsum<<<1, 512, 0, stream>>>(bsum, boff, NB, rowptr, N, E);
    k_scan_final<<<NB, 256, 0, stream>>>(cnt, boff, rowptr, N);
    k_fill<<<(E + B - 1) / B, B, 0, stream>>>(row, col, rowptr, pos, src, E);

    // ---- layer 1 (aggregate xs, then transform) ----
    k_xs<<<(N * 16 + B - 1) / B, B, 0, stream>>>(x, dis, xs, N * 16);
    k_l1<<<(N + 3) / 4, 256, 0, stream>>>(xs, src, rowptr, dis, W1, b1, h, N);

    // ---- layer 2 transform (pre-scaled messages) ----
    k_h2s<<<(N * NCLS + B - 1) / B, B, 0, stream>>>(h, W2, dis, h2s, N);

    // ---- layer 2 aggregate + log-softmax + mean ----
    k_zero_out<<<1, 64, 0, stream>>>(out);
    k_lsm2<<<NB, 256, 0, stream>>>(h2s, src, rowptr, dis, b2, out, N, 1.0f / (float)N);
}

// Round 3
// 507.539 us; speedup vs baseline: 2.3980x; 1.1644x over previous
//
#include <hip/hip_runtime.h>
#include <math.h>

#define IN_F 64
#define HID 128
#define NCLS 10

// ---------- utility ----------
__global__ void k_zero_int(int* __restrict__ p, int n) {
    int i = blockIdx.x * blockDim.x + threadIdx.x;
    if (i < n) p[i] = 0;
}

__global__ void k_zero_out(float* __restrict__ out) {
    if (threadIdx.x < NCLS) out[threadIdx.x] = 0.f;
}

// ---------- degree histogram over targets ----------
__global__ void k_hist(const int* __restrict__ col, int* __restrict__ cnt, int E) {
    int i = blockIdx.x * blockDim.x + threadIdx.x;
    if (i < E) atomicAdd(&cnt[col[i]], 1);
}

__global__ void k_dis(const int* __restrict__ cnt, float* __restrict__ dis, int n) {
    int i = blockIdx.x * blockDim.x + threadIdx.x;
    if (i < n) dis[i] = rsqrtf(1.0f + (float)cnt[i]);  // +1 self-loop
}

// ---------- 3-kernel exclusive scan (cnt -> rowptr) ----------
__global__ void k_blocksum(const int* __restrict__ cnt, int* __restrict__ bsum, int n) {
    __shared__ int s[256];
    int i = blockIdx.x * 256 + threadIdx.x;
    s[threadIdx.x] = (i < n) ? cnt[i] : 0;
    __syncthreads();
    for (int off = 128; off > 0; off >>= 1) {
        if (threadIdx.x < off) s[threadIdx.x] += s[threadIdx.x + off];
        __syncthreads();
    }
    if (threadIdx.x == 0) bsum[blockIdx.x] = s[0];
}

__global__ void k_scan_bsum(const int* __restrict__ bsum, int* __restrict__ boff, int nb,
                            int* __restrict__ rowptr, int n, int E) {
    __shared__ int s[512];
    int t = threadIdx.x;
    int v = (t < nb) ? bsum[t] : 0;
    s[t] = v;
    __syncthreads();
    for (int off = 1; off < 512; off <<= 1) {
        int tmp = (t >= off) ? s[t - off] : 0;
        __syncthreads();
        s[t] += tmp;
        __syncthreads();
    }
    if (t < nb) boff[t] = s[t] - v;  // exclusive
    if (t == 0) rowptr[n] = E;
}

__global__ void k_scan_final(const int* __restrict__ cnt, const int* __restrict__ boff,
                             int* __restrict__ rowptr, int n) {
    __shared__ int s[256];
    int i = blockIdx.x * 256 + threadIdx.x;
    int v = (i < n) ? cnt[i] : 0;
    s[threadIdx.x] = v;
    __syncthreads();
    for (int off = 1; off < 256; off <<= 1) {
        int tmp = (threadIdx.x >= off) ? s[threadIdx.x - off] : 0;
        __syncthreads();
        s[threadIdx.x] += tmp;
        __syncthreads();
    }
    if (i < n) rowptr[i] = boff[blockIdx.x] + s[threadIdx.x] - v;  // exclusive
}

// ---------- CSR fill: src list sorted by target ----------
__global__ void k_fill(const int* __restrict__ row, const int* __restrict__ col,
                       const int* __restrict__ rowptr, int* __restrict__ pos,
                       int* __restrict__ src, int E) {
    int e = blockIdx.x * blockDim.x + threadIdx.x;
    if (e >= E) return;
    int c = col[e];
    int p = rowptr[c] + atomicAdd(&pos[c], 1);
    src[p] = row[e];
}

// ---------- xs = x * dis[node] ----------
__global__ void k_xs(const float* __restrict__ x, const float* __restrict__ dis,
                     float* __restrict__ xs, int n16) {
    int i = blockIdx.x * blockDim.x + threadIdx.x;
    if (i >= n16) return;
    float d = dis[i >> 4];  // 16 float4s per node (64 feats)
    float4 v = ((const float4*)x)[i];
    v.x *= d; v.y *= d; v.z *= d; v.w *= d;
    ((float4*)xs)[i] = v;
}

// ---------- fused gather1 + GEMM1 + bias + relu ----------
// one wave per node; 16 lanes x float4 per row; 4 edge slots/wave, unroll x2
// => 8 independent 256B row-loads in flight per wave
__global__ __launch_bounds__(256) void k_l1(const float* __restrict__ xs,
                                            const int* __restrict__ src,
                                            const int* __restrict__ rowptr,
                                            const float* __restrict__ dis,
                                            const float* __restrict__ W1,
                                            const float* __restrict__ b1,
                                            float* __restrict__ h, int n) {
    __shared__ float hacc[4][64];
    int w = threadIdx.x >> 6, lane = threadIdx.x & 63;
    int q = lane >> 4;      // edge slot 0..3
    int f4 = lane & 15;     // float4 chunk within the 64-float row
    int i = blockIdx.x * 4 + w;
    float4 acc = make_float4(0.f, 0.f, 0.f, 0.f);
    float d = 0.f;
    if (i < n) {
        d = dis[i];
        if (q == 0)  // self-loop term counted once
            acc = ((const float4*)(xs + (size_t)i * IN_F))[f4];
        int end = rowptr[i + 1];
        int e = rowptr[i] + q;
        for (; e + 4 < end; e += 8) {
            int s0 = src[e];
            int s1 = src[e + 4];
            float4 v0 = ((const float4*)(xs + (size_t)s0 * IN_F))[f4];
            float4 v1 = ((const float4*)(xs + (size_t)s1 * IN_F))[f4];
            acc.x += v0.x + v1.x;
            acc.y += v0.y + v1.y;
            acc.z += v0.z + v1.z;
            acc.w += v0.w + v1.w;
        }
        if (e < end) {
            int s = src[e];
            float4 v = ((const float4*)(xs + (size_t)s * IN_F))[f4];
            acc.x += v.x;
            acc.y += v.y;
            acc.z += v.z;
            acc.w += v.w;
        }
    }
    // combine the 4 edge slots: xor butterfly over lane bits 4 and 5
    acc.x += __shfl_xor(acc.x, 16, 64);
    acc.y += __shfl_xor(acc.y, 16, 64);
    acc.z += __shfl_xor(acc.z, 16, 64);
    acc.w += __shfl_xor(acc.w, 16, 64);
    acc.x += __shfl_xor(acc.x, 32, 64);
    acc.y += __shfl_xor(acc.y, 32, 64);
    acc.z += __shfl_xor(acc.z, 32, 64);
    acc.w += __shfl_xor(acc.w, 32, 64);
    if (q == 0) {
        acc.x *= d; acc.y *= d; acc.z *= d; acc.w *= d;
        ((float4*)hacc[w])[f4] = acc;
    }
    __syncthreads();
    if (i < n) {
        float h0 = b1[lane], h1 = b1[lane + 64];
#pragma unroll
        for (int k = 0; k < IN_F; ++k) {
            float a = hacc[w][k];  // LDS broadcast
            h0 = fmaf(a, W1[k * HID + lane], h0);
            h1 = fmaf(a, W1[k * HID + lane + 64], h1);
        }
        h[(size_t)i * HID + lane] = fmaxf(h0, 0.f);
        h[(size_t)i * HID + lane + 64] = fmaxf(h1, 0.f);
    }
}

// ---------- h2s[i,c] = dis[i] * sum_k h[i,k] W2[k,c] ----------
__global__ void k_h2s(const float* __restrict__ h, const float* __restrict__ W2,
                      const float* __restrict__ dis, float* __restrict__ h2s, int n) {
    int idx = blockIdx.x * blockDim.x + threadIdx.x;
    if (idx >= n * NCLS) return;
    int node = idx / NCLS;
    int c = idx - node * NCLS;
    const float* hr = h + (size_t)node * HID;
    float acc = 0.f;
#pragma unroll
    for (int k = 0; k < HID; k += 4) {
        float4 hv = *(const float4*)(hr + k);
        acc = fmaf(hv.x, W2[(k + 0) * NCLS + c], acc);
        acc = fmaf(hv.y, W2[(k + 1) * NCLS + c], acc);
        acc = fmaf(hv.z, W2[(k + 2) * NCLS + c], acc);
        acc = fmaf(hv.w, W2[(k + 3) * NCLS + c], acc);
    }
    h2s[idx] = acc * dis[node];
}

// ---------- fused gather2 + b2 + log-softmax + mean-reduce ----------
__global__ void k_lsm2(const float* __restrict__ h2s, const int* __restrict__ src,
                       const int* __restrict__ rowptr, const float* __restrict__ dis,
                       const float* __restrict__ b2, float* __restrict__ out, int n,
                       float inv_n) {
    __shared__ float sred[NCLS];
    if (threadIdx.x < NCLS) sred[threadIdx.x] = 0.f;
    __syncthreads();
    int i = blockIdx.x * blockDim.x + threadIdx.x;
    float loc[NCLS];
#pragma unroll
    for (int c = 0; c < NCLS; ++c) loc[c] = 0.f;
    if (i < n) {
        float a[NCLS], a2[NCLS];
        const float* self = h2s + (size_t)i * NCLS;
#pragma unroll
        for (int c = 0; c < NCLS; c += 2) {
            float2 v = *(const float2*)(self + c);
            a[c] = v.x;
            a[c + 1] = v.y;
            a2[c] = 0.f;
            a2[c + 1] = 0.f;
        }
        int beg = rowptr[i], end = rowptr[i + 1];
        int e = beg;
        for (; e + 1 < end; e += 2) {  // 2 independent accumulator chains
            const float* p0 = h2s + (size_t)src[e] * NCLS;
            const float* p1 = h2s + (size_t)src[e + 1] * NCLS;
#pragma unroll
            for (int c = 0; c < NCLS; c += 2) {
                float2 v0 = *(const float2*)(p0 + c);
                float2 v1 = *(const float2*)(p1 + c);
                a[c] += v0.x;
                a[c + 1] += v0.y;
                a2[c] += v1.x;
                a2[c + 1] += v1.y;
            }
        }
        if (e < end) {
            const float* p = h2s + (size_t)src[e] * NCLS;
#pragma unroll
            for (int c = 0; c < NCLS; c += 2) {
                float2 v = *(const float2*)(p + c);
                a[c] += v.x;
                a[c + 1] += v.y;
            }
        }
        float d = dis[i];
        float vv[NCLS];
        float m = -1e30f;
#pragma unroll
        for (int c = 0; c < NCLS; ++c) {
            vv[c] = b2[c] + d * (a[c] + a2[c]);
            m = fmaxf(m, vv[c]);
        }
        float se = 0.f;
#pragma unroll
        for (int c = 0; c < NCLS; ++c) se += __expf(vv[c] - m);
        float lse = m + __logf(se);
#pragma unroll
        for (int c = 0; c < NCLS; ++c) loc[c] = vv[c] - lse;
    }
#pragma unroll
    for (int c = 0; c < NCLS; ++c) atomicAdd(&sred[c], loc[c]);
    __syncthreads();
    if (threadIdx.x < NCLS) atomicAdd(&out[threadIdx.x], sred[threadIdx.x] * inv_n);
}

extern "C" void kernel_launch(void* const* d_in, const int* in_sizes, int n_in,
                              void* d_out, int out_size, void* d_ws, size_t ws_size,
                              hipStream_t stream) {
    const float* x = (const float*)d_in[0];
    const int* eidx = (const int*)d_in[1];
    const float* W1 = (const float*)d_in[2];
    const float* b1 = (const float*)d_in[3];
    const float* W2 = (const float*)d_in[4];
    const float* b2 = (const float*)d_in[5];
    float* out = (float*)d_out;

    const int N = in_sizes[0] / IN_F;  // 100000
    const int E = in_sizes[1] / 2;     // 1600000
    const int* row = eidx;             // sources
    const int* col = eidx + E;         // targets

    const int NB = (N + 255) / 256;  // scan blocks (391 <= 512)

    // workspace layout (4-byte words, 1024-word aligned)
    size_t o = 0;
    auto alloc = [&](size_t words) {
        size_t r = o;
        o += (words + 1023) & ~(size_t)1023;
        return r;
    };
    float* ws = (float*)d_ws;
    float* dis = ws + alloc(N);
    float* xs = ws + alloc((size_t)N * IN_F);
    float* h = ws + alloc((size_t)N * HID);
    float* h2s = ws + alloc((size_t)N * NCLS);
    int* src = (int*)(ws + alloc(E));
    int* rowptr = (int*)(ws + alloc(N + 1));
    int* cnt = (int*)(ws + alloc(N));
    int* pos = (int*)(ws + alloc(N));
    int* bsum = (int*)(ws + alloc(1024));
    int* boff = (int*)(ws + alloc(1024));

    const int B = 256;

    // ---- CSR build + degrees ----
    k_zero_int<<<(N + B - 1) / B, B, 0, stream>>>(cnt, N);
    k_zero_int<<<(N + B - 1) / B, B, 0, stream>>>(pos, N);
    k_hist<<<(E + B - 1) / B, B, 0, stream>>>(col, cnt, E);
    k_dis<<<(N + B - 1) / B, B, 0, stream>>>(cnt, dis, N);
    k_blocksum<<<NB, 256, 0, stream>>>(cnt, bsum, N);
    k_scan_bsum<<<1, 512, 0, stream>>>(bsum, boff, NB, rowptr, N, E);
    k_scan_final<<<NB, 256, 0, stream>>>(cnt, boff, rowptr, N);
    k_fill<<<(E + B - 1) / B, B, 0, stream>>>(row, col, rowptr, pos, src, E);

    // ---- layer 1 (aggregate xs, then transform) ----
    k_xs<<<(N * 16 + B - 1) / B, B, 0, stream>>>(x, dis, xs, N * 16);
    k_l1<<<(N + 3) / 4, 256, 0, stream>>>(xs, src, rowptr, dis, W1, b1, h, N);

    // ---- layer 2 transform (pre-scaled messages) ----
    k_h2s<<<(N * NCLS + B - 1) / B, B, 0, stream>>>(h, W2, dis, h2s, N);

    // ---- layer 2 aggregate + log-softmax + mean ----
    k_zero_out<<<1, 64, 0, stream>>>(out);
    k_lsm2<<<NB, 256, 0, stream>>>(h2s, src, rowptr, dis, b2, out, N, 1.0f / (float)N);
}